// Round 11
// baseline (246.974 us; speedup 1.0000x reference)
//
#include <hip/hip_runtime.h>

// Problem constants
#define LQ   2048
#define BQ   2
#define HID  1024
#define NH   16
#define DH   64
#define SCALE 0.125f
#define L2E  1.44269504088896f
#define C1   0.18033688011f     // SCALE * log2(e)
#define EXPOFF 23.0831206542f   // 16 * log2(e); fixed softmax max M=16
#define MASKNEG (-1024.0f)      // masked-key additive bias

using short8  = __attribute__((ext_vector_type(8))) short;
using ushort8 = __attribute__((ext_vector_type(8))) unsigned short;
using f32x4   = __attribute__((ext_vector_type(4))) float;
typedef unsigned short u16;
typedef __attribute__((ext_vector_type(2))) __bf16 bf16x2;

__device__ inline u16 f2bf(float x) {
    unsigned int u = __float_as_uint(x);
    u = (u + 0x7fffu + ((u >> 16) & 1u)) >> 16;   // RNE
    return (u16)u;
}

#if defined(__has_builtin)
#if __has_builtin(__builtin_amdgcn_cvt_pk_bf16_f32)
#define HAVE_PKBF 1
#endif
#if __has_builtin(__builtin_amdgcn_exp2f)
#define HAVE_EXP2 1
#endif
#endif

__device__ inline unsigned int pkbf(float a, float b) {
#ifdef HAVE_PKBF
    bf16x2 r = __builtin_amdgcn_cvt_pk_bf16_f32(a, b);
    return __builtin_bit_cast(unsigned int, r);
#else
    return (unsigned int)f2bf(a) | ((unsigned int)f2bf(b) << 16);
#endif
}

__device__ inline float fexp2(float x) {
#ifdef HAVE_EXP2
    return __builtin_amdgcn_exp2f(x);
#else
    return exp2f(x);
#endif
}

// async global->LDS, 16B per lane; LDS dest = wave-uniform base + lane*16
__device__ inline void gl_lds16(const void* g, void* l) {
    __builtin_amdgcn_global_load_lds(
        (const __attribute__((address_space(1))) void*)g,
        (__attribute__((address_space(3))) void*)l, 16, 0, 0);
}

// counted waits (rule #18: sched_barrier(0) right after each asm waitcnt)
__device__ inline void wvm4() { asm volatile("s_waitcnt vmcnt(4)" ::: "memory"); __builtin_amdgcn_sched_barrier(0); }
__device__ inline void wvm3() { asm volatile("s_waitcnt vmcnt(3)" ::: "memory"); __builtin_amdgcn_sched_barrier(0); }
__device__ inline void wvm0() { asm volatile("s_waitcnt vmcnt(0)" ::: "memory"); __builtin_amdgcn_sched_barrier(0); }
__device__ inline void wlg0() { asm volatile("s_waitcnt lgkmcnt(0)" ::: "memory"); __builtin_amdgcn_sched_barrier(0); }
__device__ inline void sbar() {
    __builtin_amdgcn_sched_barrier(0);
    __builtin_amdgcn_s_barrier();
    __builtin_amdgcn_sched_barrier(0);
}

// ---------------------------------------------------------------------------
// castw: cast 7 tensors fp32->bf16 (y=0..6) + mask decode (y==7, x==0).
// ---------------------------------------------------------------------------
struct CastArgs {
    const float* s[7];
    u16* d[7];
    int n[7];
    const unsigned char* mraw;
    float* mout;
    int mn;
};

__global__ __launch_bounds__(256) void castw(CastArgs a) {
    const int y = blockIdx.y;
    const int t = threadIdx.x;
    if (y == 7) {
        if (blockIdx.x != 0) return;
        __shared__ int cnt;
        if (t == 0) cnt = 0;
        __syncthreads();
        int local = 0;
        for (int i = t; i < a.mn; i += 256)
            if ((i & 3) && a.mraw[i]) local++;
        atomicAdd(&cnt, local);
        __syncthreads();
        bool isInt32 = (cnt == 0);
        const int* mi = (const int*)a.mraw;
        for (int i = t; i < a.mn; i += 256) {
            const bool m = isInt32 ? (mi[i] != 0) : (a.mraw[i] != 0);
            a.mout[i] = m ? (MASKNEG - EXPOFF) : (-EXPOFF);
        }
        return;
    }
    const float* s = a.s[y];
    u16* d = a.d[y];
    const int n4 = a.n[y] >> 2;
    for (int i = blockIdx.x * 256 + t; i < n4; i += gridDim.x * 256) {
        float4 v = *(const float4*)(s + (size_t)i * 4);
        uint2 p;
        p.x = pkbf(v.x, v.y);
        p.y = pkbf(v.z, v.w);
        *(uint2*)(d + (size_t)i * 4) = p;
    }
}

// ---------------------------------------------------------------------------
// Batched QKV MFMA bf16 GEMM v6: R8's 8-wave counted-vmcnt skeleton +
// XCD-aware block swizzle. Grid 768 linear; swz=(lid&7)*96+(lid>>3) gives
// each XCD a contiguous chunk of 96 logical blocks = 3 B-panels (768 KB,
// L2-resident) -> B fetched once per XCD instead of 8x round-robin.
// ---------------------------------------------------------------------------
struct QkvArgs {
    const u16* A[3];
    const u16* W[3];
    const float* bias[3];
    u16* out[3];
};

__global__ __launch_bounds__(512) void gemm_qkv(QkvArgs ga) {
    __shared__ u16 As[2][128][64];
    __shared__ u16 Bs[2][128][64];

    // XCD swizzle: hw round-robins linear id % 8 across XCDs; remap so each
    // XCD owns logical ids [c*96, (c+1)*96) = 3 consecutive (y,z) B-panels.
    const int lid = blockIdx.x + 32 * (blockIdx.y + 8 * blockIdx.z);
    const int swz = (lid & 7) * 96 + (lid >> 3);
    const int xx = swz & 31;          // m-block 0..31
    const int yy = (swz >> 5) & 7;    // n-block 0..7
    const int z  = swz >> 8;          // tensor 0..2

    const u16* A = ga.A[z];
    const u16* W = ga.W[z];
    const float* bias = ga.bias[z];
    u16* outp = ga.out[z];

    const int t = threadIdx.x;
    const int m0 = xx * 128;
    const int n0 = yy * 128;
    const int lane = t & 63;
    const int lane15 = lane & 15;
    const int quad = lane >> 4;
    const int w = t >> 6;              // wave 0..7
    const int wm = (w >> 1) * 32;      // 4 m-groups of 32 rows
    const int wn = (w & 1) * 64;       // 2 n-groups of 64 cols

    const int lrow = lane >> 3;                 // 0..7
    const int ch = (lane & 7) ^ lrow;           // source chunk (slot = lane&7)
    const u16* aS = A + (size_t)(m0 + 16 * w + lrow) * HID + 8 * ch;
    const u16* bS = W + (size_t)(n0 + 16 * w + lrow) * HID + 8 * ch;

    const int s0 = (quad ^ (lane15 & 7)) * 8;
    const int s1 = ((4 + quad) ^ (lane15 & 7)) * 8;

    f32x4 acc[2][4];
#pragma unroll
    for (int i = 0; i < 2; i++)
#pragma unroll
        for (int j = 0; j < 4; j++) acc[i][j] = (f32x4){0,0,0,0};

#define QKV_STAGE(kt, buf)                                                          \
    {                                                                               \
        _Pragma("unroll")                                                           \
        for (int i = 0; i < 2; i++) {                                               \
            gl_lds16(aS + (size_t)(8 * i) * HID + 64 * (kt), &As[buf][16 * w + 8 * i][0]); \
            gl_lds16(bS + (size_t)(8 * i) * HID + 64 * (kt), &Bs[buf][16 * w + 8 * i][0]); \
        }                                                                           \
    }

    QKV_STAGE(0, 0);
    QKV_STAGE(1, 1);

    for (int kt = 0; kt < 16; ++kt) {
        if (kt < 15) wvm4(); else wvm0();   // retire tile kt's 4 loads (per wave)
        sbar();                              // publish tile kt to all waves

        const int pb = kt & 1;
        short8 af0[2], af1[2], bf0[4], bf1[4];
#pragma unroll
        for (int i = 0; i < 2; i++) {
            const u16* ar = &As[pb][wm + i * 16 + lane15][0];
            af0[i] = *(const short8*)(ar + s0);
            af1[i] = *(const short8*)(ar + s1);
        }
#pragma unroll
        for (int j = 0; j < 4; j++) {
            const u16* br = &Bs[pb][wn + j * 16 + lane15][0];
            bf0[j] = *(const short8*)(br + s0);
            bf1[j] = *(const short8*)(br + s1);
        }
        wlg0();                              // frags in regs
        sbar();                              // all waves done reading buf[pb]
        if (kt + 2 < 16) QKV_STAGE(kt + 2, pb);

#pragma unroll
        for (int mi = 0; mi < 2; mi++)
#pragma unroll
            for (int ni = 0; ni < 4; ni++) {
                acc[mi][ni] = __builtin_amdgcn_mfma_f32_16x16x32_bf16(af0[mi], bf0[ni], acc[mi][ni], 0, 0, 0);
                acc[mi][ni] = __builtin_amdgcn_mfma_f32_16x16x32_bf16(af1[mi], bf1[ni], acc[mi][ni], 0, 0, 0);
            }
    }
#undef QKV_STAGE

#pragma unroll
    for (int mi = 0; mi < 2; mi++) {
#pragma unroll
        for (int ni = 0; ni < 4; ni++) {
            const int n = n0 + wn + ni * 16 + lane15;
            const float bv = bias[n];
            const int h = n >> 6, d = n & 63;
#pragma unroll
            for (int r = 0; r < 4; r++) {
                const int m = m0 + wm + mi * 16 + quad * 4 + r;
                const float c = acc[mi][ni][r] + bv;
                const int b = m & 1, l = m >> 1;
                if (z < 2) {
                    outp[(((size_t)(b * NH + h)) * LQ + l) * DH + d] = f2bf(c);
                } else {
                    outp[(((size_t)(b * NH + h)) * DH + d) * LQ + l] = f2bf(c);
                }
            }
        }
    }
}

// ---------------------------------------------------------------------------
// FC GEMM v2 (fp32 out): 128x64 tile, BK=64, counted-vmcnt depth-2,
// 512 THREADS / 8 WAVES (wave owns 32x32, acc[2][2]).
// Per wave per stage: 2 A + 1 B gl_lds -> vmcnt(3) retire.
// ---------------------------------------------------------------------------
__global__ __launch_bounds__(512) void gemm_fc(const u16* __restrict__ A,
                                               const u16* __restrict__ W,
                                               const float* __restrict__ bias,
                                               float* __restrict__ outp) {
    __shared__ u16 As[2][128][64];
    __shared__ u16 Bs[2][64][64];

    const int t = threadIdx.x;
    const int m0 = blockIdx.x * 128;
    const int n0 = blockIdx.y * 64;
    const int lane = t & 63;
    const int lane15 = lane & 15;
    const int quad = lane >> 4;
    const int w = t >> 6;              // wave 0..7
    const int wm = (w >> 1) * 32;      // 4 m-groups of 32 rows
    const int wn = (w & 1) * 32;       // 2 n-groups of 32 cols

    const int lrow = lane >> 3;
    const int ch = (lane & 7) ^ lrow;
    const u16* aS = A + (size_t)(m0 + 16 * w + lrow) * HID + 8 * ch;
    const u16* bS = W + (size_t)(n0 + 8 * w + lrow) * HID + 8 * ch;

    const int s0 = (quad ^ (lane15 & 7)) * 8;
    const int s1 = ((4 + quad) ^ (lane15 & 7)) * 8;

    f32x4 acc[2][2];
#pragma unroll
    for (int i = 0; i < 2; i++)
#pragma unroll
        for (int j = 0; j < 2; j++) acc[i][j] = (f32x4){0,0,0,0};

#define FC_STAGE(kt, buf)                                                           \
    {                                                                               \
        _Pragma("unroll")                                                           \
        for (int i = 0; i < 2; i++)                                                 \
            gl_lds16(aS + (size_t)(8 * i) * HID + 64 * (kt), &As[buf][16 * w + 8 * i][0]); \
        gl_lds16(bS + 64 * (kt), &Bs[buf][8 * w][0]);                               \
    }

    FC_STAGE(0, 0);
    FC_STAGE(1, 1);

    for (int kt = 0; kt < 16; ++kt) {
        if (kt < 15) wvm3(); else wvm0();
        sbar();

        const int pb = kt & 1;
        short8 af0[2], af1[2], bf0[2], bf1[2];
#pragma unroll
        for (int i = 0; i < 2; i++) {
            const u16* ar = &As[pb][wm + i * 16 + lane15][0];
            af0[i] = *(const short8*)(ar + s0);
            af1[i] = *(const short8*)(ar + s1);
        }
#pragma unroll
        for (int j = 0; j < 2; j++) {
            const u16* br = &Bs[pb][wn + j * 16 + lane15][0];
            bf0[j] = *(const short8*)(br + s0);
            bf1[j] = *(const short8*)(br + s1);
        }
        wlg0();
        sbar();
        if (kt + 2 < 16) FC_STAGE(kt + 2, pb);

#pragma unroll
        for (int mi = 0; mi < 2; mi++)
#pragma unroll
            for (int ni = 0; ni < 2; ni++) {
                acc[mi][ni] = __builtin_amdgcn_mfma_f32_16x16x32_bf16(af0[mi], bf0[ni], acc[mi][ni], 0, 0, 0);
                acc[mi][ni] = __builtin_amdgcn_mfma_f32_16x16x32_bf16(af1[mi], bf1[ni], acc[mi][ni], 0, 0, 0);
            }
    }
#undef FC_STAGE

#pragma unroll
    for (int mi = 0; mi < 2; mi++) {
#pragma unroll
        for (int ni = 0; ni < 2; ni++) {
            const int n = n0 + wn + ni * 16 + lane15;
            const float bv = bias[n];
#pragma unroll
            for (int r = 0; r < 4; r++) {
                const int m = m0 + wm + mi * 16 + quad * 4 + r;
                outp[(size_t)m * HID + n] = acc[mi][ni][r] + bv;
            }
        }
    }
}

// ---------------------------------------------------------------------------
// MFMA bf16 flash attention v6 (R8 best, 53.0 us): 4 waves x 32 q-rows,
// counted-vmcnt chunk pipeline, depth-2 staging, vmcnt(4), mask row in
// LDS, K/V frags to regs before re-stage barrier.
// ---------------------------------------------------------------------------
#define PSTR 72

__global__ __launch_bounds__(256, 2) void attn_kernel(const u16* __restrict__ Qg,
                                                      const u16* __restrict__ Kg,
                                                      const u16* __restrict__ Vtg,
                                                      const float* __restrict__ maskF,
                                                      const float* __restrict__ tao,
                                                      u16* __restrict__ Xa) {
    __shared__ u16 Ks[2][64][64];   // [buf][key][d], chunk c of row r at slot c^(r&7)
    __shared__ u16 Vt[2][64][64];   // [buf][d][key], same swizzle
    __shared__ u16 PT[128][PSTR];   // wave-private rows (wave w owns rows 32w..32w+31)
    __shared__ float smaskL[LQ];    // mask bias row, loaded once (8 KB)

    const int bh = blockIdx.x;
    const int q0 = blockIdx.y * 128;
    const int b = bh >> 4;
    const int h = bh & 15;
    const int t = threadIdx.x;
    const int w = t >> 6;            // wave 0..3
    const int lane = t & 63;
    const int lane15 = lane & 15;
    const int quad = lane >> 4;

    const u16* Kbase = Kg + (size_t)bh * LQ * DH;
    const u16* Vtbase = Vtg + (size_t)bh * DH * LQ;
    const float* mrow = maskF + b * LQ;

    const float tv = tao[h];
    const float t2 = tv * tv;
    const float nb = -0.5f / (t2 * t2);
    const float nb2 = nb * L2E;             // negative
    const float sqn = sqrtf(-nb2);
    const float R = sqrtf(-40.0f / nb2) + 1.0f;   // conservative (superset)

    // contiguous chunk range covering q0..q0+127
    int c_lo = (int)floorf(((float)q0 - R) * (1.0f / 64.0f));
    int c_hi = (int)floorf(((float)(q0 + 127) + R) * (1.0f / 64.0f));
    if (c_lo < 0) c_lo = 0;
    if (c_hi > (LQ / 64 - 1)) c_hi = LQ / 64 - 1;
    if (c_hi < c_lo) c_hi = c_lo;
    const int c1 = (c_lo + 1 <= c_hi) ? (c_lo + 1) : c_hi;

    // staging lane mapping: inst covers 8 rows x 8 swizzled 16B chunks
    const int lr = lane >> 3;        // 0..7
    const int sch = (lane & 7) ^ lr; // XOR-swizzled source chunk
    const u16* kS0 = Kbase + (size_t)(16 * w + lr) * DH + 8 * sch;
    const u16* kS1 = Kbase + (size_t)(16 * w + 8 + lr) * DH + 8 * sch;
    const u16* vS0 = Vtbase + (size_t)(16 * w + lr) * LQ + 8 * sch;
    const u16* vS1 = Vtbase + (size_t)(16 * w + 8 + lr) * LQ + 8 * sch;

#define ATT_STAGE(cc, buf)                                             \
    {                                                                  \
        gl_lds16(kS0 + (size_t)(cc) * (64 * DH), &Ks[buf][16 * w][0]); \
        gl_lds16(kS1 + (size_t)(cc) * (64 * DH), &Ks[buf][16 * w + 8][0]); \
        gl_lds16(vS0 + 64 * (cc), &Vt[buf][16 * w][0]);                \
        gl_lds16(vS1 + 64 * (cc), &Vt[buf][16 * w + 8][0]);            \
    }

    // Q fragments (registers), two 16-row halves per wave
    const int qrow0 = q0 + w * 32 + lane15;
    const int qrow1 = qrow0 + 16;
    short8 qA00, qA01, qA10, qA11;
    {
        const u16* qp0 = Qg + ((size_t)bh * LQ + qrow0) * DH + quad * 8;
        qA00 = *(const short8*)(qp0);
        qA01 = *(const short8*)(qp0 + 32);
        const u16* qp1 = Qg + ((size_t)bh * LQ + qrow1) * DH + quad * 8;
        qA10 = *(const short8*)(qp1);
        qA11 = *(const short8*)(qp1 + 32);
    }
    // mask row -> regs (2 float4/thread), then stages, then mask -> LDS
    const float4 mT0 = *(const float4*)(mrow + 4 * t);
    const float4 mT1 = *(const float4*)(mrow + 1024 + 4 * t);
    __builtin_amdgcn_sched_barrier(0);
    ATT_STAGE(c_lo, 0);
    ATT_STAGE(c1, 1);
    __builtin_amdgcn_sched_barrier(0);
    *(float4*)&smaskL[4 * t] = mT0;          // compiler waits mask vmcnt here
    *(float4*)&smaskL[1024 + 4 * t] = mT1;
    wlg0();                                   // own ds_writes complete

    const int s0 = (quad ^ (lane15 & 7)) * 8;
    const int s1 = ((4 + quad) ^ (lane15 & 7)) * 8;

    // pre-scaled per-element key offsets: (kt*16+r)*sqn
    float crs[16];
#pragma unroll
    for (int i = 0; i < 16; i++)
        crs[i] = (float)((i >> 2) * 16 + (i & 3)) * sqn;

    // bf16 ones A-fragment for MFMA row-sum
    short8 ones;
#pragma unroll
    for (int i = 0; i < 8; i++) ones[i] = (short)0x3F80;

    f32x4 O0[4], O1[4];
#pragma unroll
    for (int mt = 0; mt < 4; mt++) { O0[mt] = (f32x4){0,0,0,0}; O1[mt] = (f32x4){0,0,0,0}; }
    f32x4 Lac0 = (f32x4){0,0,0,0};
    f32x4 Lac1 = (f32x4){0,0,0,0};

    const float eb00 = (float)(qrow0 - quad * 4);
    const float eb01 = (float)(qrow1 - quad * 4);
    const int prow0 = w * 32 + lane15;
    const int prow1 = prow0 + 16;

    for (int c = c_lo; c <= c_hi; ++c) {
        if (c < c_hi) wvm4(); else wvm0();   // retire chunk c's 4 loads
        sbar();                               // publish chunk c (+ mask on 1st iter)

        const int pb = (c - c_lo) & 1;

        // K + V fragments -> regs (ALL reads of buf pb happen here)
        short8 ka[4], kb[4], va[4], vb[4];
#pragma unroll
        for (int kt = 0; kt < 4; kt++) {
            const u16* kr = &Ks[pb][kt * 16 + lane15][0];
            ka[kt] = *(const short8*)(kr + s0);
            kb[kt] = *(const short8*)(kr + s1);
            const u16* vr = &Vt[pb][kt * 16 + lane15][0];
            va[kt] = *(const short8*)(vr + s0);
            vb[kt] = *(const short8*)(vr + s1);
        }

        // QK^T for BOTH halves; K frags reused from registers
        f32x4 S0[4], S1[4];
#pragma unroll
        for (int kt = 0; kt < 4; kt++) {
            S0[kt] = __builtin_amdgcn_mfma_f32_16x16x32_bf16(ka[kt], qA00, (f32x4){0,0,0,0}, 0, 0, 0);
            S0[kt] = __builtin_amdgcn_mfma_f32_16x16x32_bf16(kb[kt], qA01, S0[kt], 0, 0, 0);
            S1[kt] = __builtin_amdgcn_mfma_f32_16x16x32_bf16(ka[kt], qA10, (f32x4){0,0,0,0}, 0, 0, 0);
            S1[kt] = __builtin_amdgcn_mfma_f32_16x16x32_bf16(kb[kt], qA11, S1[kt], 0, 0, 0);
        }

        wlg0();                               // all LDS reads of buf pb done
        sbar();                               // every wave past its reads
        if (c + 2 <= c_hi) ATT_STAGE(c + 2, pb);   // overwrite buf pb (lands by iter c+2)

        // mask bias from LDS (quad-uniform broadcast, lgkm-side)
        float4 mv[4];
#pragma unroll
        for (int kt = 0; kt < 4; kt++)
            mv[kt] = *(const float4*)&smaskL[64 * c + kt * 16 + quad * 4];

        // softmax (fixed max): p = exp2(S*C1 - dp^2 + maskbias), both halves
        const float ebS0 = (eb00 - (float)(64 * c)) * sqn;
        const float ebS1 = (eb01 - (float)(64 * c)) * sqn;
#pragma unroll
        for (int kt = 0; kt < 4; kt++) {
            float pr0[4], pr1[4];
#pragma unroll
            for (int r = 0; r < 4; r++) {
                const float mb = ((const float*)&mv[kt])[r];
                const float dp0 = ebS0 - crs[kt * 4 + r];
                const float dp1 = ebS1 - crs[kt * 4 + r];
                pr0[r] = fexp2(fmaf(S0[kt][r], C1, fmaf(-dp0, dp0, mb)));
                pr1[r] = fexp2(fmaf(S1[kt][r], C1, fmaf(-dp1, dp1, mb)));
            }
            uint2 pk0, pk1;
            pk0.x = pkbf(pr0[0], pr0[1]);
            pk0.y = pkbf(pr0[2], pr0[3]);
            pk1.x = pkbf(pr1[0], pr1[1]);
            pk1.y = pkbf(pr1[2], pr1[3]);
            *(uint2*)&PT[prow0][kt * 16 + quad * 4] = pk0;
            *(uint2*)&PT[prow1][kt * 16 + quad * 4] = pk1;
        }

        // P fragments (wave-private rows; same-wave cross-lane after lgkm)
        const short8 pB00 = *(const short8*)&PT[prow0][quad * 8];
        const short8 pB01 = *(const short8*)&PT[prow0][32 + quad * 8];
        const short8 pB10 = *(const short8*)&PT[prow1][quad * 8];
        const short8 pB11 = *(const short8*)&PT[prow1][32 + quad * 8];
        Lac0 = __builtin_amdgcn_mfma_f32_16x16x32_bf16(ones, pB00, Lac0, 0, 0, 0);
        Lac0 = __builtin_amdgcn_mfma_f32_16x16x32_bf16(ones, pB01, Lac0, 0, 0, 0);
        Lac1 = __builtin_amdgcn_mfma_f32_16x16x32_bf16(ones, pB10, Lac1, 0, 0, 0);
        Lac1 = __builtin_amdgcn_mfma_f32_16x16x32_bf16(ones, pB11, Lac1, 0, 0, 0);

        // PV for BOTH halves; V from regs (safe vs. re-stage of buf pb)
#pragma unroll
        for (int mt = 0; mt < 4; mt++) {
            O0[mt] = __builtin_amdgcn_mfma_f32_16x16x32_bf16(va[mt], pB00, O0[mt], 0, 0, 0);
            O0[mt] = __builtin_amdgcn_mfma_f32_16x16x32_bf16(vb[mt], pB01, O0[mt], 0, 0, 0);
            O1[mt] = __builtin_amdgcn_mfma_f32_16x16x32_bf16(va[mt], pB10, O1[mt], 0, 0, 0);
            O1[mt] = __builtin_amdgcn_mfma_f32_16x16x32_bf16(vb[mt], pB11, O1[mt], 0, 0, 0);
        }
    }
#undef ATT_STAGE

    {
        const float inv0 = 1.0f / Lac0[0];
        u16* dst0 = Xa + ((size_t)qrow0 * BQ + b) * HID + h * DH;
#pragma unroll
        for (int mt = 0; mt < 4; mt++) {
            uint2 pk2;
            pk2.x = pkbf(O0[mt][0] * inv0, O0[mt][1] * inv0);
            pk2.y = pkbf(O0[mt][2] * inv0, O0[mt][3] * inv0);
            *(uint2*)(dst0 + mt * 16 + quad * 4) = pk2;
        }
        const float inv1 = 1.0f / Lac1[0];
        u16* dst1 = Xa + ((size_t)qrow1 * BQ + b) * HID + h * DH;
#pragma unroll
        for (int mt = 0; mt < 4; mt++) {
            uint2 pk2;
            pk2.x = pkbf(O1[mt][0] * inv1, O1[mt][1] * inv1);
            pk2.y = pkbf(O1[mt][2] * inv1, O1[mt][3] * inv1);
            *(uint2*)(dst1 + mt * 16 + quad * 4) = pk2;
        }
    }
}

// ---------------------------------------------------------------------------
extern "C" void kernel_launch(void* const* d_in, const int* in_sizes, int n_in,
                              void* d_out, int out_size, void* d_ws, size_t ws_size,
                              hipStream_t stream) {
    const float* q    = (const float*)d_in[0];
    const float* k    = (const float*)d_in[1];
    const float* v    = (const float*)d_in[2];
    const void*  mask = d_in[3];
    const float* wq   = (const float*)d_in[4];
    const float* wk   = (const float*)d_in[5];
    const float* wv   = (const float*)d_in[6];
    const float* wfc  = (const float*)d_in[7];
    const float* bq   = (const float*)d_in[8];
    const float* bk   = (const float*)d_in[9];
    const float* bv   = (const float*)d_in[10];
    const float* bfc  = (const float*)d_in[11];
    const float* tao  = (const float*)d_in[12];

    const size_t NE = (size_t)LQ * BQ * HID;  // 4,194,304
    const size_t NW = (size_t)HID * HID;      // 1,048,576
    u16* base = (u16*)d_ws;
    u16* Qp    = base;            // [bh][l][d]
    u16* Kp    = base + NE;       // [bh][l][d]
    u16* Vtp   = base + 2 * NE;   // [bh][d][l]
    u16* Xa    = base + 3 * NE;
    u16* qbf   = base + 4 * NE;
    u16* kbf   = base + 5 * NE;
    u16* vbf   = base + 6 * NE;
    u16* wqbf  = base + 7 * NE;
    u16* wkbf  = wqbf + NW;
    u16* wvbf  = wkbf + NW;
    u16* wfcbf = wvbf + NW;
    float* maskF = (float*)(wfcbf + NW);

    CastArgs ca;
    ca.s[0] = q;   ca.d[0] = qbf;   ca.n[0] = (int)NE;
    ca.s[1] = k;   ca.d[1] = kbf;   ca.n[1] = (int)NE;
    ca.s[2] = v;   ca.d[2] = vbf;   ca.n[2] = (int)NE;
    ca.s[3] = wq;  ca.d[3] = wqbf;  ca.n[3] = (int)NW;
    ca.s[4] = wk;  ca.d[4] = wkbf;  ca.n[4] = (int)NW;
    ca.s[5] = wv;  ca.d[5] = wvbf;  ca.n[5] = (int)NW;
    ca.s[6] = wfc; ca.d[6] = wfcbf; ca.n[6] = (int)NW;
    ca.mraw = (const unsigned char*)mask;
    ca.mout = maskF;
    ca.mn = BQ * LQ;
    castw<<<dim3(256, 8), 256, 0, stream>>>(ca);

    QkvArgs ga;
    ga.A[0] = qbf;  ga.W[0] = wqbf;  ga.bias[0] = bq;  ga.out[0] = Qp;
    ga.A[1] = kbf;  ga.W[1] = wkbf;  ga.bias[1] = bk;  ga.out[1] = Kp;
    ga.A[2] = vbf;  ga.W[2] = wvbf;  ga.bias[2] = bv;  ga.out[2] = Vtp;
    gemm_qkv<<<dim3(32, 8, 3), 512, 0, stream>>>(ga);

    attn_kernel<<<dim3(32, 16), 256, 0, stream>>>(Qp, Kp, Vtp, maskF, tao, Xa);

    gemm_fc<<<dim3(32, 16), 512, 0, stream>>>(Xa, wfcbf, bfc, (float*)d_out);
}

// Round 12
// 219.579 us; speedup vs baseline: 1.1248x; 1.1248x over previous
//
#include <hip/hip_runtime.h>

// Problem constants
#define LQ   2048
#define BQ   2
#define HID  1024
#define NH   16
#define DH   64
#define SCALE 0.125f
#define L2E  1.44269504088896f
#define C1   0.18033688011f     // SCALE * log2(e)
#define EXPOFF 23.0831206542f   // 16 * log2(e); fixed softmax max M=16
#define MASKNEG (-1024.0f)      // masked-key additive bias

using short8  = __attribute__((ext_vector_type(8))) short;
using ushort8 = __attribute__((ext_vector_type(8))) unsigned short;
using f32x4   = __attribute__((ext_vector_type(4))) float;
typedef unsigned short u16;
typedef __attribute__((ext_vector_type(2))) __bf16 bf16x2;

__device__ inline u16 f2bf(float x) {
    unsigned int u = __float_as_uint(x);
    u = (u + 0x7fffu + ((u >> 16) & 1u)) >> 16;   // RNE
    return (u16)u;
}

#if defined(__has_builtin)
#if __has_builtin(__builtin_amdgcn_cvt_pk_bf16_f32)
#define HAVE_PKBF 1
#endif
#if __has_builtin(__builtin_amdgcn_exp2f)
#define HAVE_EXP2 1
#endif
#endif

__device__ inline unsigned int pkbf(float a, float b) {
#ifdef HAVE_PKBF
    bf16x2 r = __builtin_amdgcn_cvt_pk_bf16_f32(a, b);
    return __builtin_bit_cast(unsigned int, r);
#else
    return (unsigned int)f2bf(a) | ((unsigned int)f2bf(b) << 16);
#endif
}

__device__ inline float fexp2(float x) {
#ifdef HAVE_EXP2
    return __builtin_amdgcn_exp2f(x);
#else
    return exp2f(x);
#endif
}

// async global->LDS, 16B per lane; LDS dest = wave-uniform base + lane*16
__device__ inline void gl_lds16(const void* g, void* l) {
    __builtin_amdgcn_global_load_lds(
        (const __attribute__((address_space(1))) void*)g,
        (__attribute__((address_space(3))) void*)l, 16, 0, 0);
}

// counted waits (rule #18: sched_barrier(0) right after each asm waitcnt)
__device__ inline void wvm6() { asm volatile("s_waitcnt vmcnt(6)" ::: "memory"); __builtin_amdgcn_sched_barrier(0); }
__device__ inline void wvm4() { asm volatile("s_waitcnt vmcnt(4)" ::: "memory"); __builtin_amdgcn_sched_barrier(0); }
__device__ inline void wvm0() { asm volatile("s_waitcnt vmcnt(0)" ::: "memory"); __builtin_amdgcn_sched_barrier(0); }
__device__ inline void wlg0() { asm volatile("s_waitcnt lgkmcnt(0)" ::: "memory"); __builtin_amdgcn_sched_barrier(0); }
__device__ inline void sbar() {
    __builtin_amdgcn_sched_barrier(0);
    __builtin_amdgcn_s_barrier();
    __builtin_amdgcn_sched_barrier(0);
}

// ---------------------------------------------------------------------------
// castw: cast 7 tensors fp32->bf16 (y=0..6) + mask decode (y==7, x==0).
// Mask emits FLOAT additive bias per key: -EXPOFF (keep) or
// MASKNEG-EXPOFF (masked; exp2 underflows to exactly 0).
// ---------------------------------------------------------------------------
struct CastArgs {
    const float* s[7];
    u16* d[7];
    int n[7];
    const unsigned char* mraw;
    float* mout;
    int mn;
};

__global__ __launch_bounds__(256) void castw(CastArgs a) {
    const int y = blockIdx.y;
    const int t = threadIdx.x;
    if (y == 7) {
        if (blockIdx.x != 0) return;
        __shared__ int cnt;
        if (t == 0) cnt = 0;
        __syncthreads();
        int local = 0;
        for (int i = t; i < a.mn; i += 256)
            if ((i & 3) && a.mraw[i]) local++;
        atomicAdd(&cnt, local);
        __syncthreads();
        bool isInt32 = (cnt == 0);
        const int* mi = (const int*)a.mraw;
        for (int i = t; i < a.mn; i += 256) {
            const bool m = isInt32 ? (mi[i] != 0) : (a.mraw[i] != 0);
            a.mout[i] = m ? (MASKNEG - EXPOFF) : (-EXPOFF);
        }
        return;
    }
    const float* s = a.s[y];
    u16* d = a.d[y];
    const int n4 = a.n[y] >> 2;
    for (int i = blockIdx.x * 256 + t; i < n4; i += gridDim.x * 256) {
        float4 v = *(const float4*)(s + (size_t)i * 4);
        uint2 p;
        p.x = pkbf(v.x, v.y);
        p.y = pkbf(v.z, v.w);
        *(uint2*)(d + (size_t)i * 4) = p;
    }
}

// ---------------------------------------------------------------------------
// Batched QKV MFMA bf16 GEMM v5 (R8 best): 128x128 tile, BK=64,
// counted-vmcnt depth-2, 512 threads / 8 waves, vmcnt(4) retire.
// NO XCD swizzle (R11 showed it doubles FETCH: A-locality loss > B gain).
// ---------------------------------------------------------------------------
struct QkvArgs {
    const u16* A[3];
    const u16* W[3];
    const float* bias[3];
    u16* out[3];
};

__global__ __launch_bounds__(512) void gemm_qkv(QkvArgs ga) {
    __shared__ u16 As[2][128][64];
    __shared__ u16 Bs[2][128][64];

    const int z = blockIdx.z;
    const u16* A = ga.A[z];
    const u16* W = ga.W[z];
    const float* bias = ga.bias[z];
    u16* outp = ga.out[z];

    const int t = threadIdx.x;
    const int m0 = blockIdx.x * 128;
    const int n0 = blockIdx.y * 128;
    const int lane = t & 63;
    const int lane15 = lane & 15;
    const int quad = lane >> 4;
    const int w = t >> 6;              // wave 0..7
    const int wm = (w >> 1) * 32;      // 4 m-groups of 32 rows
    const int wn = (w & 1) * 64;       // 2 n-groups of 64 cols

    const int lrow = lane >> 3;                 // 0..7
    const int ch = (lane & 7) ^ lrow;           // source chunk (slot = lane&7)
    const u16* aS = A + (size_t)(m0 + 16 * w + lrow) * HID + 8 * ch;
    const u16* bS = W + (size_t)(n0 + 16 * w + lrow) * HID + 8 * ch;

    const int s0 = (quad ^ (lane15 & 7)) * 8;
    const int s1 = ((4 + quad) ^ (lane15 & 7)) * 8;

    f32x4 acc[2][4];
#pragma unroll
    for (int i = 0; i < 2; i++)
#pragma unroll
        for (int j = 0; j < 4; j++) acc[i][j] = (f32x4){0,0,0,0};

#define QKV_STAGE(kt, buf)                                                          \
    {                                                                               \
        _Pragma("unroll")                                                           \
        for (int i = 0; i < 2; i++) {                                               \
            gl_lds16(aS + (size_t)(8 * i) * HID + 64 * (kt), &As[buf][16 * w + 8 * i][0]); \
            gl_lds16(bS + (size_t)(8 * i) * HID + 64 * (kt), &Bs[buf][16 * w + 8 * i][0]); \
        }                                                                           \
    }

    QKV_STAGE(0, 0);
    QKV_STAGE(1, 1);

    for (int kt = 0; kt < 16; ++kt) {
        if (kt < 15) wvm4(); else wvm0();   // retire tile kt's 4 loads (per wave)
        sbar();                              // publish tile kt to all waves

        const int pb = kt & 1;
        short8 af0[2], af1[2], bf0[4], bf1[4];
#pragma unroll
        for (int i = 0; i < 2; i++) {
            const u16* ar = &As[pb][wm + i * 16 + lane15][0];
            af0[i] = *(const short8*)(ar + s0);
            af1[i] = *(const short8*)(ar + s1);
        }
#pragma unroll
        for (int j = 0; j < 4; j++) {
            const u16* br = &Bs[pb][wn + j * 16 + lane15][0];
            bf0[j] = *(const short8*)(br + s0);
            bf1[j] = *(const short8*)(br + s1);
        }
        wlg0();                              // frags in regs
        sbar();                              // all waves done reading buf[pb]
        if (kt + 2 < 16) QKV_STAGE(kt + 2, pb);  // overwrite buf[pb]; lands by iter kt+2

#pragma unroll
        for (int mi = 0; mi < 2; mi++)
#pragma unroll
            for (int ni = 0; ni < 4; ni++) {
                acc[mi][ni] = __builtin_amdgcn_mfma_f32_16x16x32_bf16(af0[mi], bf0[ni], acc[mi][ni], 0, 0, 0);
                acc[mi][ni] = __builtin_amdgcn_mfma_f32_16x16x32_bf16(af1[mi], bf1[ni], acc[mi][ni], 0, 0, 0);
            }
    }
#undef QKV_STAGE

#pragma unroll
    for (int mi = 0; mi < 2; mi++) {
#pragma unroll
        for (int ni = 0; ni < 4; ni++) {
            const int n = n0 + wn + ni * 16 + lane15;
            const float bv = bias[n];
            const int h = n >> 6, d = n & 63;
#pragma unroll
            for (int r = 0; r < 4; r++) {
                const int m = m0 + wm + mi * 16 + quad * 4 + r;
                const float c = acc[mi][ni][r] + bv;
                const int b = m & 1, l = m >> 1;
                if (z < 2) {
                    outp[(((size_t)(b * NH + h)) * LQ + l) * DH + d] = f2bf(c);
                } else {
                    outp[(((size_t)(b * NH + h)) * DH + d) * LQ + l] = f2bf(c);
                }
            }
        }
    }
}

// ---------------------------------------------------------------------------
// FC GEMM v1 (R8 best, fp32 out): 128x64 tile, BK=64, 256 threads / 4 waves,
// counted-vmcnt depth-2, vmcnt(6). (v2 8-wave regressed ~2x in R11: only
// 8 MFMA per 2 barriers per wave -- lever needs >=16 MFMA/barrier.)
// ---------------------------------------------------------------------------
__global__ __launch_bounds__(256) void gemm_fc(const u16* __restrict__ A,
                                               const u16* __restrict__ W,
                                               const float* __restrict__ bias,
                                               float* __restrict__ outp) {
    __shared__ u16 As[2][128][64];
    __shared__ u16 Bs[2][64][64];

    const int t = threadIdx.x;
    const int m0 = blockIdx.x * 128;
    const int n0 = blockIdx.y * 64;
    const int lane = t & 63;
    const int lane15 = lane & 15;
    const int quad = lane >> 4;
    const int w = t >> 6;
    const int wm = (w >> 1) * 64;
    const int wn = (w & 1) * 32;

    const int lrow = lane >> 3;
    const int ch = (lane & 7) ^ ((lane >> 3) & 7);
    const u16* aS = A + (size_t)(m0 + 32 * w + lrow) * HID + 8 * ch;
    const u16* bS = W + (size_t)(n0 + 16 * w + lrow) * HID + 8 * ch;

    const int s0 = (quad ^ (lane15 & 7)) * 8;
    const int s1 = ((4 + quad) ^ (lane15 & 7)) * 8;

    f32x4 acc[4][2];
#pragma unroll
    for (int i = 0; i < 4; i++)
#pragma unroll
        for (int j = 0; j < 2; j++) acc[i][j] = (f32x4){0,0,0,0};

#define FC_STAGE(kt, buf)                                                           \
    {                                                                               \
        _Pragma("unroll")                                                           \
        for (int i = 0; i < 4; i++)                                                 \
            gl_lds16(aS + (size_t)(8 * i) * HID + 64 * (kt), &As[buf][32 * w + 8 * i][0]); \
        _Pragma("unroll")                                                           \
        for (int i = 0; i < 2; i++)                                                 \
            gl_lds16(bS + (size_t)(8 * i) * HID + 64 * (kt), &Bs[buf][16 * w + 8 * i][0]); \
    }

    FC_STAGE(0, 0);
    FC_STAGE(1, 1);

    for (int kt = 0; kt < 16; ++kt) {
        if (kt < 15) wvm6(); else wvm0();
        sbar();

        const int pb = kt & 1;
        short8 af0[4], af1[4], bf0[2], bf1[2];
#pragma unroll
        for (int i = 0; i < 4; i++) {
            const u16* ar = &As[pb][wm + i * 16 + lane15][0];
            af0[i] = *(const short8*)(ar + s0);
            af1[i] = *(const short8*)(ar + s1);
        }
#pragma unroll
        for (int j = 0; j < 2; j++) {
            const u16* br = &Bs[pb][wn + j * 16 + lane15][0];
            bf0[j] = *(const short8*)(br + s0);
            bf1[j] = *(const short8*)(br + s1);
        }
        wlg0();
        sbar();
        if (kt + 2 < 16) FC_STAGE(kt + 2, pb);

#pragma unroll
        for (int mi = 0; mi < 4; mi++)
#pragma unroll
            for (int ni = 0; ni < 2; ni++) {
                acc[mi][ni] = __builtin_amdgcn_mfma_f32_16x16x32_bf16(af0[mi], bf0[ni], acc[mi][ni], 0, 0, 0);
                acc[mi][ni] = __builtin_amdgcn_mfma_f32_16x16x32_bf16(af1[mi], bf1[ni], acc[mi][ni], 0, 0, 0);
            }
    }
#undef FC_STAGE

#pragma unroll
    for (int mi = 0; mi < 4; mi++) {
#pragma unroll
        for (int ni = 0; ni < 2; ni++) {
            const int n = n0 + wn + ni * 16 + lane15;
            const float bv = bias[n];
#pragma unroll
            for (int r = 0; r < 4; r++) {
                const int m = m0 + wm + mi * 16 + quad * 4 + r;
                outp[(size_t)m * HID + n] = acc[mi][ni][r] + bv;
            }
        }
    }
}

// ---------------------------------------------------------------------------
// MFMA bf16 flash attention v6 (R8 best) + relaxed tile-skip threshold:
// 2^-40 -> 2^-26 (R 746->601, ~17% fewer chunks; dropped mass <= 2048*2^-26
// ~= 3e-5 relative, excluded from num AND denom -> error ~1e-4 << 5e-3 tol).
// 4 waves x 32 q-rows, counted-vmcnt chunk pipeline, depth-2, vmcnt(4),
// mask row in LDS, K/V frags to regs before re-stage barrier.
// ---------------------------------------------------------------------------
#define PSTR 72

__global__ __launch_bounds__(256, 2) void attn_kernel(const u16* __restrict__ Qg,
                                                      const u16* __restrict__ Kg,
                                                      const u16* __restrict__ Vtg,
                                                      const float* __restrict__ maskF,
                                                      const float* __restrict__ tao,
                                                      u16* __restrict__ Xa) {
    __shared__ u16 Ks[2][64][64];   // [buf][key][d], chunk c of row r at slot c^(r&7)
    __shared__ u16 Vt[2][64][64];   // [buf][d][key], same swizzle
    __shared__ u16 PT[128][PSTR];   // wave-private rows (wave w owns rows 32w..32w+31)
    __shared__ float smaskL[LQ];    // mask bias row, loaded once (8 KB)

    const int bh = blockIdx.x;
    const int q0 = blockIdx.y * 128;
    const int b = bh >> 4;
    const int h = bh & 15;
    const int t = threadIdx.x;
    const int w = t >> 6;            // wave 0..3
    const int lane = t & 63;
    const int lane15 = lane & 15;
    const int quad = lane >> 4;

    const u16* Kbase = Kg + (size_t)bh * LQ * DH;
    const u16* Vtbase = Vtg + (size_t)bh * DH * LQ;
    const float* mrow = maskF + b * LQ;

    const float tv = tao[h];
    const float t2 = tv * tv;
    const float nb = -0.5f / (t2 * t2);
    const float nb2 = nb * L2E;             // negative
    const float sqn = sqrtf(-nb2);
    const float R = sqrtf(-26.0f / nb2) + 1.0f;   // 2^-26 skip threshold

    // contiguous chunk range covering q0..q0+127
    int c_lo = (int)floorf(((float)q0 - R) * (1.0f / 64.0f));
    int c_hi = (int)floorf(((float)(q0 + 127) + R) * (1.0f / 64.0f));
    if (c_lo < 0) c_lo = 0;
    if (c_hi > (LQ / 64 - 1)) c_hi = LQ / 64 - 1;
    if (c_hi < c_lo) c_hi = c_lo;
    const int c1 = (c_lo + 1 <= c_hi) ? (c_lo + 1) : c_hi;

    // staging lane mapping: inst covers 8 rows x 8 swizzled 16B chunks
    const int lr = lane >> 3;        // 0..7
    const int sch = (lane & 7) ^ lr; // XOR-swizzled source chunk
    const u16* kS0 = Kbase + (size_t)(16 * w + lr) * DH + 8 * sch;
    const u16* kS1 = Kbase + (size_t)(16 * w + 8 + lr) * DH + 8 * sch;
    const u16* vS0 = Vtbase + (size_t)(16 * w + lr) * LQ + 8 * sch;
    const u16* vS1 = Vtbase + (size_t)(16 * w + 8 + lr) * LQ + 8 * sch;

#define ATT_STAGE(cc, buf)                                             \
    {                                                                  \
        gl_lds16(kS0 + (size_t)(cc) * (64 * DH), &Ks[buf][16 * w][0]); \
        gl_lds16(kS1 + (size_t)(cc) * (64 * DH), &Ks[buf][16 * w + 8][0]); \
        gl_lds16(vS0 + 64 * (cc), &Vt[buf][16 * w][0]);                \
        gl_lds16(vS1 + 64 * (cc), &Vt[buf][16 * w + 8][0]);            \
    }

    // Q fragments (registers), two 16-row halves per wave
    const int qrow0 = q0 + w * 32 + lane15;
    const int qrow1 = qrow0 + 16;
    short8 qA00, qA01, qA10, qA11;
    {
        const u16* qp0 = Qg + ((size_t)bh * LQ + qrow0) * DH + quad * 8;
        qA00 = *(const short8*)(qp0);
        qA01 = *(const short8*)(qp0 + 32);
        const u16* qp1 = Qg + ((size_t)bh * LQ + qrow1) * DH + quad * 8;
        qA10 = *(const short8*)(qp1);
        qA11 = *(const short8*)(qp1 + 32);
    }
    // mask row -> regs (2 float4/thread), then stages, then mask -> LDS
    const float4 mT0 = *(const float4*)(mrow + 4 * t);
    const float4 mT1 = *(const float4*)(mrow + 1024 + 4 * t);
    __builtin_amdgcn_sched_barrier(0);
    ATT_STAGE(c_lo, 0);
    ATT_STAGE(c1, 1);
    __builtin_amdgcn_sched_barrier(0);
    *(float4*)&smaskL[4 * t] = mT0;          // compiler waits mask vmcnt here
    *(float4*)&smaskL[1024 + 4 * t] = mT1;
    wlg0();                                   // own ds_writes complete

    const int s0 = (quad ^ (lane15 & 7)) * 8;
    const int s1 = ((4 + quad) ^ (lane15 & 7)) * 8;

    // pre-scaled per-element key offsets: (kt*16+r)*sqn
    float crs[16];
#pragma unroll
    for (int i = 0; i < 16; i++)
        crs[i] = (float)((i >> 2) * 16 + (i & 3)) * sqn;

    // bf16 ones A-fragment for MFMA row-sum
    short8 ones;
#pragma unroll
    for (int i = 0; i < 8; i++) ones[i] = (short)0x3F80;

    f32x4 O0[4], O1[4];
#pragma unroll
    for (int mt = 0; mt < 4; mt++) { O0[mt] = (f32x4){0,0,0,0}; O1[mt] = (f32x4){0,0,0,0}; }
    f32x4 Lac0 = (f32x4){0,0,0,0};
    f32x4 Lac1 = (f32x4){0,0,0,0};

    const float eb00 = (float)(qrow0 - quad * 4);
    const float eb01 = (float)(qrow1 - quad * 4);
    const int prow0 = w * 32 + lane15;
    const int prow1 = prow0 + 16;

    for (int c = c_lo; c <= c_hi; ++c) {
        if (c < c_hi) wvm4(); else wvm0();   // retire chunk c's 4 loads
        sbar();                               // publish chunk c (+ mask on 1st iter)

        const int pb = (c - c_lo) & 1;

        // K + V fragments -> regs (ALL reads of buf pb happen here)
        short8 ka[4], kb[4], va[4], vb[4];
#pragma unroll
        for (int kt = 0; kt < 4; kt++) {
            const u16* kr = &Ks[pb][kt * 16 + lane15][0];
            ka[kt] = *(const short8*)(kr + s0);
            kb[kt] = *(const short8*)(kr + s1);
            const u16* vr = &Vt[pb][kt * 16 + lane15][0];
            va[kt] = *(const short8*)(vr + s0);
            vb[kt] = *(const short8*)(vr + s1);
        }

        // QK^T for BOTH halves; K frags reused from registers
        f32x4 S0[4], S1[4];
#pragma unroll
        for (int kt = 0; kt < 4; kt++) {
            S0[kt] = __builtin_amdgcn_mfma_f32_16x16x32_bf16(ka[kt], qA00, (f32x4){0,0,0,0}, 0, 0, 0);
            S0[kt] = __builtin_amdgcn_mfma_f32_16x16x32_bf16(kb[kt], qA01, S0[kt], 0, 0, 0);
            S1[kt] = __builtin_amdgcn_mfma_f32_16x16x32_bf16(ka[kt], qA10, (f32x4){0,0,0,0}, 0, 0, 0);
            S1[kt] = __builtin_amdgcn_mfma_f32_16x16x32_bf16(kb[kt], qA11, S1[kt], 0, 0, 0);
        }

        wlg0();                               // all LDS reads of buf pb done
        sbar();                               // every wave past its reads
        if (c + 2 <= c_hi) ATT_STAGE(c + 2, pb);   // overwrite buf pb (lands by iter c+2)

        // mask bias from LDS (quad-uniform broadcast, lgkm-side)
        float4 mv[4];
#pragma unroll
        for (int kt = 0; kt < 4; kt++)
            mv[kt] = *(const float4*)&smaskL[64 * c + kt * 16 + quad * 4];

        // softmax (fixed max): p = exp2(S*C1 - dp^2 + maskbias), both halves
        const float ebS0 = (eb00 - (float)(64 * c)) * sqn;
        const float ebS1 = (eb01 - (float)(64 * c)) * sqn;
#pragma unroll
        for (int kt = 0; kt < 4; kt++) {
            float pr0[4], pr1[4];
#pragma unroll
            for (int r = 0; r < 4; r++) {
                const float mb = ((const float*)&mv[kt])[r];
                const float dp0 = ebS0 - crs[kt * 4 + r];
                const float dp1 = ebS1 - crs[kt * 4 + r];
                pr0[r] = fexp2(fmaf(S0[kt][r], C1, fmaf(-dp0, dp0, mb)));
                pr1[r] = fexp2(fmaf(S1[kt][r], C1, fmaf(-dp1, dp1, mb)));
            }
            uint2 pk0, pk1;
            pk0.x = pkbf(pr0[0], pr0[1]);
            pk0.y = pkbf(pr0[2], pr0[3]);
            pk1.x = pkbf(pr1[0], pr1[1]);
            pk1.y = pkbf(pr1[2], pr1[3]);
            *(uint2*)&PT[prow0][kt * 16 + quad * 4] = pk0;
            *(uint2*)&PT[prow1][kt * 16 + quad * 4] = pk1;
        }

        // P fragments (wave-private rows; same-wave cross-lane after lgkm)
        const short8 pB00 = *(const short8*)&PT[prow0][quad * 8];
        const short8 pB01 = *(const short8*)&PT[prow0][32 + quad * 8];
        const short8 pB10 = *(const short8*)&PT[prow1][quad * 8];
        const short8 pB11 = *(const short8*)&PT[prow1][32 + quad * 8];
        Lac0 = __builtin_amdgcn_mfma_f32_16x16x32_bf16(ones, pB00, Lac0, 0, 0, 0);
        Lac0 = __builtin_amdgcn_mfma_f32_16x16x32_bf16(ones, pB01, Lac0, 0, 0, 0);
        Lac1 = __builtin_amdgcn_mfma_f32_16x16x32_bf16(ones, pB10, Lac1, 0, 0, 0);
        Lac1 = __builtin_amdgcn_mfma_f32_16x16x32_bf16(ones, pB11, Lac1, 0, 0, 0);

        // PV for BOTH halves; V from regs (safe vs. re-stage of buf pb)
#pragma unroll
        for (int mt = 0; mt < 4; mt++) {
            O0[mt] = __builtin_amdgcn_mfma_f32_16x16x32_bf16(va[mt], pB00, O0[mt], 0, 0, 0);
            O0[mt] = __builtin_amdgcn_mfma_f32_16x16x32_bf16(vb[mt], pB01, O0[mt], 0, 0, 0);
            O1[mt] = __builtin_amdgcn_mfma_f32_16x16x32_bf16(va[mt], pB10, O1[mt], 0, 0, 0);
            O1[mt] = __builtin_amdgcn_mfma_f32_16x16x32_bf16(vb[mt], pB11, O1[mt], 0, 0, 0);
        }
    }
#undef ATT_STAGE

    {
        const float inv0 = 1.0f / Lac0[0];
        u16* dst0 = Xa + ((size_t)qrow0 * BQ + b) * HID + h * DH;
#pragma unroll
        for (int mt = 0; mt < 4; mt++) {
            uint2 pk2;
            pk2.x = pkbf(O0[mt][0] * inv0, O0[mt][1] * inv0);
            pk2.y = pkbf(O0[mt][2] * inv0, O0[mt][3] * inv0);
            *(uint2*)(dst0 + mt * 16 + quad * 4) = pk2;
        }
        const float inv1 = 1.0f / Lac1[0];
        u16* dst1 = Xa + ((size_t)qrow1 * BQ + b) * HID + h * DH;
#pragma unroll
        for (int mt = 0; mt < 4; mt++) {
            uint2 pk2;
            pk2.x = pkbf(O1[mt][0] * inv1, O1[mt][1] * inv1);
            pk2.y = pkbf(O1[mt][2] * inv1, O1[mt][3] * inv1);
            *(uint2*)(dst1 + mt * 16 + quad * 4) = pk2;
        }
    }
}

// ---------------------------------------------------------------------------
extern "C" void kernel_launch(void* const* d_in, const int* in_sizes, int n_in,
                              void* d_out, int out_size, void* d_ws, size_t ws_size,
                              hipStream_t stream) {
    const float* q    = (const float*)d_in[0];
    const float* k    = (const float*)d_in[1];
    const float* v    = (const float*)d_in[2];
    const void*  mask = d_in[3];
    const float* wq   = (const float*)d_in[4];
    const float* wk   = (const float*)d_in[5];
    const float* wv   = (const float*)d_in[6];
    const float* wfc  = (const float*)d_in[7];
    const float* bq   = (const float*)d_in[8];
    const float* bk   = (const float*)d_in[9];
    const float* bv   = (const float*)d_in[10];
    const float* bfc  = (const float*)d_in[11];
    const float* tao  = (const float*)d_in[12];

    const size_t NE = (size_t)LQ * BQ * HID;  // 4,194,304
    const size_t NW = (size_t)HID * HID;      // 1,048,576
    u16* base = (u16*)d_ws;
    u16* Qp    = base;            // [bh][l][d]
    u16* Kp    = base + NE;       // [bh][l][d]
    u16* Vtp   = base + 2 * NE;   // [bh][d][l]
    u16* Xa    = base + 3 * NE;
    u16* qbf   = base + 4 * NE;
    u16* kbf   = base + 5 * NE;
    u16* vbf   = base + 6 * NE;
    u16* wqbf  = base + 7 * NE;
    u16* wkbf  = wqbf + NW;
    u16* wvbf  = wkbf + NW;
    u16* wfcbf = wvbf + NW;
    float* maskF = (float*)(wfcbf + NW);

    CastArgs ca;
    ca.s[0] = q;   ca.d[0] = qbf;   ca.n[0] = (int)NE;
    ca.s[1] = k;   ca.d[1] = kbf;   ca.n[1] = (int)NE;
    ca.s[2] = v;   ca.d[2] = vbf;   ca.n[2] = (int)NE;
    ca.s[3] = wq;  ca.d[3] = wqbf;  ca.n[3] = (int)NW;
    ca.s[4] = wk;  ca.d[4] = wkbf;  ca.n[4] = (int)NW;
    ca.s[5] = wv;  ca.d[5] = wvbf;  ca.n[5] = (int)NW;
    ca.s[6] = wfc; ca.d[6] = wfcbf; ca.n[6] = (int)NW;
    ca.mraw = (const unsigned char*)mask;
    ca.mout = maskF;
    ca.mn = BQ * LQ;
    castw<<<dim3(256, 8), 256, 0, stream>>>(ca);

    QkvArgs ga;
    ga.A[0] = qbf;  ga.W[0] = wqbf;  ga.bias[0] = bq;  ga.out[0] = Qp;
    ga.A[1] = kbf;  ga.W[1] = wkbf;  ga.bias[1] = bk;  ga.out[1] = Kp;
    ga.A[2] = vbf;  ga.W[2] = wvbf;  ga.bias[2] = bv;  ga.out[2] = Vtp;
    gemm_qkv<<<dim3(32, 8, 3), 512, 0, stream>>>(ga);

    attn_kernel<<<dim3(32, 16), 256, 0, stream>>>(Qp, Kp, Vtp, maskF, tao, Xa);

    gemm_fc<<<dim3(32, 16), 256, 0, stream>>>(Xa, wfcbf, bfc, (float*)d_out);
}

// Round 13
// 214.741 us; speedup vs baseline: 1.1501x; 1.0225x over previous
//
#include <hip/hip_runtime.h>

// Problem constants
#define LQ   2048
#define BQ   2
#define HID  1024
#define NH   16
#define DH   64
#define SCALE 0.125f
#define L2E  1.44269504088896f
#define C1   0.18033688011f     // SCALE * log2(e)
#define EXPOFF 23.0831206542f   // 16 * log2(e); fixed softmax max M=16
#define MASKNEG (-1024.0f)      // masked-key additive bias

using short8  = __attribute__((ext_vector_type(8))) short;
using ushort8 = __attribute__((ext_vector_type(8))) unsigned short;
using f32x4   = __attribute__((ext_vector_type(4))) float;
typedef unsigned short u16;
typedef __attribute__((ext_vector_type(2))) __bf16 bf16x2;

__device__ inline u16 f2bf(float x) {
    unsigned int u = __float_as_uint(x);
    u = (u + 0x7fffu + ((u >> 16) & 1u)) >> 16;   // RNE
    return (u16)u;
}

#if defined(__has_builtin)
#if __has_builtin(__builtin_amdgcn_cvt_pk_bf16_f32)
#define HAVE_PKBF 1
#endif
#if __has_builtin(__builtin_amdgcn_exp2f)
#define HAVE_EXP2 1
#endif
#endif

__device__ inline unsigned int pkbf(float a, float b) {
#ifdef HAVE_PKBF
    bf16x2 r = __builtin_amdgcn_cvt_pk_bf16_f32(a, b);
    return __builtin_bit_cast(unsigned int, r);
#else
    return (unsigned int)f2bf(a) | ((unsigned int)f2bf(b) << 16);
#endif
}

__device__ inline float fexp2(float x) {
#ifdef HAVE_EXP2
    return __builtin_amdgcn_exp2f(x);
#else
    return exp2f(x);
#endif
}

// async global->LDS, 16B per lane; LDS dest = wave-uniform base + lane*16
__device__ inline void gl_lds16(const void* g, void* l) {
    __builtin_amdgcn_global_load_lds(
        (const __attribute__((address_space(1))) void*)g,
        (__attribute__((address_space(3))) void*)l, 16, 0, 0);
}

// counted waits (rule #18: sched_barrier(0) right after each asm waitcnt)
__device__ inline void wvm6() { asm volatile("s_waitcnt vmcnt(6)" ::: "memory"); __builtin_amdgcn_sched_barrier(0); }
__device__ inline void wvm4() { asm volatile("s_waitcnt vmcnt(4)" ::: "memory"); __builtin_amdgcn_sched_barrier(0); }
__device__ inline void wvm0() { asm volatile("s_waitcnt vmcnt(0)" ::: "memory"); __builtin_amdgcn_sched_barrier(0); }
__device__ inline void wlg0() { asm volatile("s_waitcnt lgkmcnt(0)" ::: "memory"); __builtin_amdgcn_sched_barrier(0); }
__device__ inline void sbar() {
    __builtin_amdgcn_sched_barrier(0);
    __builtin_amdgcn_s_barrier();
    __builtin_amdgcn_sched_barrier(0);
}

// ---------------------------------------------------------------------------
// castw: cast 7 tensors fp32->bf16 (y=0..6) + mask decode (y==7, x==0).
// Mask emits FLOAT additive bias per key: -EXPOFF (keep) or
// MASKNEG-EXPOFF (masked; exp2 underflows to exactly 0).
// ---------------------------------------------------------------------------
struct CastArgs {
    const float* s[7];
    u16* d[7];
    int n[7];
    const unsigned char* mraw;
    float* mout;
    int mn;
};

__global__ __launch_bounds__(256) void castw(CastArgs a) {
    const int y = blockIdx.y;
    const int t = threadIdx.x;
    if (y == 7) {
        if (blockIdx.x != 0) return;
        __shared__ int cnt;
        if (t == 0) cnt = 0;
        __syncthreads();
        int local = 0;
        for (int i = t; i < a.mn; i += 256)
            if ((i & 3) && a.mraw[i]) local++;
        atomicAdd(&cnt, local);
        __syncthreads();
        bool isInt32 = (cnt == 0);
        const int* mi = (const int*)a.mraw;
        for (int i = t; i < a.mn; i += 256) {
            const bool m = isInt32 ? (mi[i] != 0) : (a.mraw[i] != 0);
            a.mout[i] = m ? (MASKNEG - EXPOFF) : (-EXPOFF);
        }
        return;
    }
    const float* s = a.s[y];
    u16* d = a.d[y];
    const int n4 = a.n[y] >> 2;
    for (int i = blockIdx.x * 256 + t; i < n4; i += gridDim.x * 256) {
        float4 v = *(const float4*)(s + (size_t)i * 4);
        uint2 p;
        p.x = pkbf(v.x, v.y);
        p.y = pkbf(v.z, v.w);
        *(uint2*)(d + (size_t)i * 4) = p;
    }
}

// ---------------------------------------------------------------------------
// Batched QKV MFMA bf16 GEMM v5 (R8 best): 128x128 tile, BK=64,
// counted-vmcnt depth-2, 512 threads / 8 waves, vmcnt(4) retire.
// NO XCD swizzle (R11 showed it doubles FETCH: A-locality loss > B gain).
// ---------------------------------------------------------------------------
struct QkvArgs {
    const u16* A[3];
    const u16* W[3];
    const float* bias[3];
    u16* out[3];
};

__global__ __launch_bounds__(512) void gemm_qkv(QkvArgs ga) {
    __shared__ u16 As[2][128][64];
    __shared__ u16 Bs[2][128][64];

    const int z = blockIdx.z;
    const u16* A = ga.A[z];
    const u16* W = ga.W[z];
    const float* bias = ga.bias[z];
    u16* outp = ga.out[z];

    const int t = threadIdx.x;
    const int m0 = blockIdx.x * 128;
    const int n0 = blockIdx.y * 128;
    const int lane = t & 63;
    const int lane15 = lane & 15;
    const int quad = lane >> 4;
    const int w = t >> 6;              // wave 0..7
    const int wm = (w >> 1) * 32;      // 4 m-groups of 32 rows
    const int wn = (w & 1) * 64;       // 2 n-groups of 64 cols

    const int lrow = lane >> 3;                 // 0..7
    const int ch = (lane & 7) ^ lrow;           // source chunk (slot = lane&7)
    const u16* aS = A + (size_t)(m0 + 16 * w + lrow) * HID + 8 * ch;
    const u16* bS = W + (size_t)(n0 + 16 * w + lrow) * HID + 8 * ch;

    const int s0 = (quad ^ (lane15 & 7)) * 8;
    const int s1 = ((4 + quad) ^ (lane15 & 7)) * 8;

    f32x4 acc[2][4];
#pragma unroll
    for (int i = 0; i < 2; i++)
#pragma unroll
        for (int j = 0; j < 4; j++) acc[i][j] = (f32x4){0,0,0,0};

#define QKV_STAGE(kt, buf)                                                          \
    {                                                                               \
        _Pragma("unroll")                                                           \
        for (int i = 0; i < 2; i++) {                                               \
            gl_lds16(aS + (size_t)(8 * i) * HID + 64 * (kt), &As[buf][16 * w + 8 * i][0]); \
            gl_lds16(bS + (size_t)(8 * i) * HID + 64 * (kt), &Bs[buf][16 * w + 8 * i][0]); \
        }                                                                           \
    }

    QKV_STAGE(0, 0);
    QKV_STAGE(1, 1);

    for (int kt = 0; kt < 16; ++kt) {
        if (kt < 15) wvm4(); else wvm0();   // retire tile kt's 4 loads (per wave)
        sbar();                              // publish tile kt to all waves

        const int pb = kt & 1;
        short8 af0[2], af1[2], bf0[4], bf1[4];
#pragma unroll
        for (int i = 0; i < 2; i++) {
            const u16* ar = &As[pb][wm + i * 16 + lane15][0];
            af0[i] = *(const short8*)(ar + s0);
            af1[i] = *(const short8*)(ar + s1);
        }
#pragma unroll
        for (int j = 0; j < 4; j++) {
            const u16* br = &Bs[pb][wn + j * 16 + lane15][0];
            bf0[j] = *(const short8*)(br + s0);
            bf1[j] = *(const short8*)(br + s1);
        }
        wlg0();                              // frags in regs
        sbar();                              // all waves done reading buf[pb]
        if (kt + 2 < 16) QKV_STAGE(kt + 2, pb);  // overwrite buf[pb]; lands by iter kt+2

#pragma unroll
        for (int mi = 0; mi < 2; mi++)
#pragma unroll
            for (int ni = 0; ni < 4; ni++) {
                acc[mi][ni] = __builtin_amdgcn_mfma_f32_16x16x32_bf16(af0[mi], bf0[ni], acc[mi][ni], 0, 0, 0);
                acc[mi][ni] = __builtin_amdgcn_mfma_f32_16x16x32_bf16(af1[mi], bf1[ni], acc[mi][ni], 0, 0, 0);
            }
    }
#undef QKV_STAGE

#pragma unroll
    for (int mi = 0; mi < 2; mi++) {
#pragma unroll
        for (int ni = 0; ni < 4; ni++) {
            const int n = n0 + wn + ni * 16 + lane15;
            const float bv = bias[n];
            const int h = n >> 6, d = n & 63;
#pragma unroll
            for (int r = 0; r < 4; r++) {
                const int m = m0 + wm + mi * 16 + quad * 4 + r;
                const float c = acc[mi][ni][r] + bv;
                const int b = m & 1, l = m >> 1;
                if (z < 2) {
                    outp[(((size_t)(b * NH + h)) * LQ + l) * DH + d] = f2bf(c);
                } else {
                    outp[(((size_t)(b * NH + h)) * DH + d) * LQ + l] = f2bf(c);
                }
            }
        }
    }
}

// ---------------------------------------------------------------------------
// FC GEMM v1 (R8 best, fp32 out): 128x64 tile, BK=64, 256 threads / 4 waves,
// counted-vmcnt depth-2, vmcnt(6).
// ---------------------------------------------------------------------------
__global__ __launch_bounds__(256) void gemm_fc(const u16* __restrict__ A,
                                               const u16* __restrict__ W,
                                               const float* __restrict__ bias,
                                               float* __restrict__ outp) {
    __shared__ u16 As[2][128][64];
    __shared__ u16 Bs[2][64][64];

    const int t = threadIdx.x;
    const int m0 = blockIdx.x * 128;
    const int n0 = blockIdx.y * 64;
    const int lane = t & 63;
    const int lane15 = lane & 15;
    const int quad = lane >> 4;
    const int w = t >> 6;
    const int wm = (w >> 1) * 64;
    const int wn = (w & 1) * 32;

    const int lrow = lane >> 3;
    const int ch = (lane & 7) ^ ((lane >> 3) & 7);
    const u16* aS = A + (size_t)(m0 + 32 * w + lrow) * HID + 8 * ch;
    const u16* bS = W + (size_t)(n0 + 16 * w + lrow) * HID + 8 * ch;

    const int s0 = (quad ^ (lane15 & 7)) * 8;
    const int s1 = ((4 + quad) ^ (lane15 & 7)) * 8;

    f32x4 acc[4][2];
#pragma unroll
    for (int i = 0; i < 4; i++)
#pragma unroll
        for (int j = 0; j < 2; j++) acc[i][j] = (f32x4){0,0,0,0};

#define FC_STAGE(kt, buf)                                                           \
    {                                                                               \
        _Pragma("unroll")                                                           \
        for (int i = 0; i < 4; i++)                                                 \
            gl_lds16(aS + (size_t)(8 * i) * HID + 64 * (kt), &As[buf][32 * w + 8 * i][0]); \
        _Pragma("unroll")                                                           \
        for (int i = 0; i < 2; i++)                                                 \
            gl_lds16(bS + (size_t)(8 * i) * HID + 64 * (kt), &Bs[buf][16 * w + 8 * i][0]); \
    }

    FC_STAGE(0, 0);
    FC_STAGE(1, 1);

    for (int kt = 0; kt < 16; ++kt) {
        if (kt < 15) wvm6(); else wvm0();
        sbar();

        const int pb = kt & 1;
        short8 af0[4], af1[4], bf0[2], bf1[2];
#pragma unroll
        for (int i = 0; i < 4; i++) {
            const u16* ar = &As[pb][wm + i * 16 + lane15][0];
            af0[i] = *(const short8*)(ar + s0);
            af1[i] = *(const short8*)(ar + s1);
        }
#pragma unroll
        for (int j = 0; j < 2; j++) {
            const u16* br = &Bs[pb][wn + j * 16 + lane15][0];
            bf0[j] = *(const short8*)(br + s0);
            bf1[j] = *(const short8*)(br + s1);
        }
        wlg0();
        sbar();
        if (kt + 2 < 16) FC_STAGE(kt + 2, pb);

#pragma unroll
        for (int mi = 0; mi < 4; mi++)
#pragma unroll
            for (int ni = 0; ni < 2; ni++) {
                acc[mi][ni] = __builtin_amdgcn_mfma_f32_16x16x32_bf16(af0[mi], bf0[ni], acc[mi][ni], 0, 0, 0);
                acc[mi][ni] = __builtin_amdgcn_mfma_f32_16x16x32_bf16(af1[mi], bf1[ni], acc[mi][ni], 0, 0, 0);
            }
    }
#undef FC_STAGE

#pragma unroll
    for (int mi = 0; mi < 4; mi++) {
#pragma unroll
        for (int ni = 0; ni < 2; ni++) {
            const int n = n0 + wn + ni * 16 + lane15;
            const float bv = bias[n];
#pragma unroll
            for (int r = 0; r < 4; r++) {
                const int m = m0 + wm + mi * 16 + quad * 4 + r;
                outp[(size_t)m * HID + n] = acc[mi][ni][r] + bv;
            }
        }
    }
}

// ---------------------------------------------------------------------------
// MFMA bf16 flash attention v6 + tile-skip threshold 2^-20 (was 2^-26 in
// R12, measured absmax bit-identical; Gaussian tail mass at 2^-20 ~ 1e-4
// relative -> output perturbation ~3e-4, 16x below the 4.9e-3 bf16 floor).
// R 602 -> 528, chunks/block 20.8 -> 18.5 (-11%).
// 4 waves x 32 q-rows, counted-vmcnt chunk pipeline, depth-2, vmcnt(4),
// mask row in LDS, K/V frags to regs before re-stage barrier.
// ---------------------------------------------------------------------------
#define PSTR 72

__global__ __launch_bounds__(256, 2) void attn_kernel(const u16* __restrict__ Qg,
                                                      const u16* __restrict__ Kg,
                                                      const u16* __restrict__ Vtg,
                                                      const float* __restrict__ maskF,
                                                      const float* __restrict__ tao,
                                                      u16* __restrict__ Xa) {
    __shared__ u16 Ks[2][64][64];   // [buf][key][d], chunk c of row r at slot c^(r&7)
    __shared__ u16 Vt[2][64][64];   // [buf][d][key], same swizzle
    __shared__ u16 PT[128][PSTR];   // wave-private rows (wave w owns rows 32w..32w+31)
    __shared__ float smaskL[LQ];    // mask bias row, loaded once (8 KB)

    const int bh = blockIdx.x;
    const int q0 = blockIdx.y * 128;
    const int b = bh >> 4;
    const int h = bh & 15;
    const int t = threadIdx.x;
    const int w = t >> 6;            // wave 0..3
    const int lane = t & 63;
    const int lane15 = lane & 15;
    const int quad = lane >> 4;

    const u16* Kbase = Kg + (size_t)bh * LQ * DH;
    const u16* Vtbase = Vtg + (size_t)bh * DH * LQ;
    const float* mrow = maskF + b * LQ;

    const float tv = tao[h];
    const float t2 = tv * tv;
    const float nb = -0.5f / (t2 * t2);
    const float nb2 = nb * L2E;             // negative
    const float sqn = sqrtf(-nb2);
    const float R = sqrtf(-20.0f / nb2) + 1.0f;   // 2^-20 skip threshold

    // contiguous chunk range covering q0..q0+127
    int c_lo = (int)floorf(((float)q0 - R) * (1.0f / 64.0f));
    int c_hi = (int)floorf(((float)(q0 + 127) + R) * (1.0f / 64.0f));
    if (c_lo < 0) c_lo = 0;
    if (c_hi > (LQ / 64 - 1)) c_hi = LQ / 64 - 1;
    if (c_hi < c_lo) c_hi = c_lo;
    const int c1 = (c_lo + 1 <= c_hi) ? (c_lo + 1) : c_hi;

    // staging lane mapping: inst covers 8 rows x 8 swizzled 16B chunks
    const int lr = lane >> 3;        // 0..7
    const int sch = (lane & 7) ^ lr; // XOR-swizzled source chunk
    const u16* kS0 = Kbase + (size_t)(16 * w + lr) * DH + 8 * sch;
    const u16* kS1 = Kbase + (size_t)(16 * w + 8 + lr) * DH + 8 * sch;
    const u16* vS0 = Vtbase + (size_t)(16 * w + lr) * LQ + 8 * sch;
    const u16* vS1 = Vtbase + (size_t)(16 * w + 8 + lr) * LQ + 8 * sch;

#define ATT_STAGE(cc, buf)                                             \
    {                                                                  \
        gl_lds16(kS0 + (size_t)(cc) * (64 * DH), &Ks[buf][16 * w][0]); \
        gl_lds16(kS1 + (size_t)(cc) * (64 * DH), &Ks[buf][16 * w + 8][0]); \
        gl_lds16(vS0 + 64 * (cc), &Vt[buf][16 * w][0]);                \
        gl_lds16(vS1 + 64 * (cc), &Vt[buf][16 * w + 8][0]);            \
    }

    // Q fragments (registers), two 16-row halves per wave
    const int qrow0 = q0 + w * 32 + lane15;
    const int qrow1 = qrow0 + 16;
    short8 qA00, qA01, qA10, qA11;
    {
        const u16* qp0 = Qg + ((size_t)bh * LQ + qrow0) * DH + quad * 8;
        qA00 = *(const short8*)(qp0);
        qA01 = *(const short8*)(qp0 + 32);
        const u16* qp1 = Qg + ((size_t)bh * LQ + qrow1) * DH + quad * 8;
        qA10 = *(const short8*)(qp1);
        qA11 = *(const short8*)(qp1 + 32);
    }
    // mask row -> regs (2 float4/thread), then stages, then mask -> LDS
    const float4 mT0 = *(const float4*)(mrow + 4 * t);
    const float4 mT1 = *(const float4*)(mrow + 1024 + 4 * t);
    __builtin_amdgcn_sched_barrier(0);
    ATT_STAGE(c_lo, 0);
    ATT_STAGE(c1, 1);
    __builtin_amdgcn_sched_barrier(0);
    *(float4*)&smaskL[4 * t] = mT0;          // compiler waits mask vmcnt here
    *(float4*)&smaskL[1024 + 4 * t] = mT1;
    wlg0();                                   // own ds_writes complete

    const int s0 = (quad ^ (lane15 & 7)) * 8;
    const int s1 = ((4 + quad) ^ (lane15 & 7)) * 8;

    // pre-scaled per-element key offsets: (kt*16+r)*sqn
    float crs[16];
#pragma unroll
    for (int i = 0; i < 16; i++)
        crs[i] = (float)((i >> 2) * 16 + (i & 3)) * sqn;

    // bf16 ones A-fragment for MFMA row-sum
    short8 ones;
#pragma unroll
    for (int i = 0; i < 8; i++) ones[i] = (short)0x3F80;

    f32x4 O0[4], O1[4];
#pragma unroll
    for (int mt = 0; mt < 4; mt++) { O0[mt] = (f32x4){0,0,0,0}; O1[mt] = (f32x4){0,0,0,0}; }
    f32x4 Lac0 = (f32x4){0,0,0,0};
    f32x4 Lac1 = (f32x4){0,0,0,0};

    const float eb00 = (float)(qrow0 - quad * 4);
    const float eb01 = (float)(qrow1 - quad * 4);
    const int prow0 = w * 32 + lane15;
    const int prow1 = prow0 + 16;

    for (int c = c_lo; c <= c_hi; ++c) {
        if (c < c_hi) wvm4(); else wvm0();   // retire chunk c's 4 loads
        sbar();                               // publish chunk c (+ mask on 1st iter)

        const int pb = (c - c_lo) & 1;

        // K + V fragments -> regs (ALL reads of buf pb happen here)
        short8 ka[4], kb[4], va[4], vb[4];
#pragma unroll
        for (int kt = 0; kt < 4; kt++) {
            const u16* kr = &Ks[pb][kt * 16 + lane15][0];
            ka[kt] = *(const short8*)(kr + s0);
            kb[kt] = *(const short8*)(kr + s1);
            const u16* vr = &Vt[pb][kt * 16 + lane15][0];
            va[kt] = *(const short8*)(vr + s0);
            vb[kt] = *(const short8*)(vr + s1);
        }

        // QK^T for BOTH halves; K frags reused from registers
        f32x4 S0[4], S1[4];
#pragma unroll
        for (int kt = 0; kt < 4; kt++) {
            S0[kt] = __builtin_amdgcn_mfma_f32_16x16x32_bf16(ka[kt], qA00, (f32x4){0,0,0,0}, 0, 0, 0);
            S0[kt] = __builtin_amdgcn_mfma_f32_16x16x32_bf16(kb[kt], qA01, S0[kt], 0, 0, 0);
            S1[kt] = __builtin_amdgcn_mfma_f32_16x16x32_bf16(ka[kt], qA10, (f32x4){0,0,0,0}, 0, 0, 0);
            S1[kt] = __builtin_amdgcn_mfma_f32_16x16x32_bf16(kb[kt], qA11, S1[kt], 0, 0, 0);
        }

        wlg0();                               // all LDS reads of buf pb done
        sbar();                               // every wave past its reads
        if (c + 2 <= c_hi) ATT_STAGE(c + 2, pb);   // overwrite buf pb (lands by iter c+2)

        // mask bias from LDS (quad-uniform broadcast, lgkm-side)
        float4 mv[4];
#pragma unroll
        for (int kt = 0; kt < 4; kt++)
            mv[kt] = *(const float4*)&smaskL[64 * c + kt * 16 + quad * 4];

        // softmax (fixed max): p = exp2(S*C1 - dp^2 + maskbias), both halves
        const float ebS0 = (eb00 - (float)(64 * c)) * sqn;
        const float ebS1 = (eb01 - (float)(64 * c)) * sqn;
#pragma unroll
        for (int kt = 0; kt < 4; kt++) {
            float pr0[4], pr1[4];
#pragma unroll
            for (int r = 0; r < 4; r++) {
                const float mb = ((const float*)&mv[kt])[r];
                const float dp0 = ebS0 - crs[kt * 4 + r];
                const float dp1 = ebS1 - crs[kt * 4 + r];
                pr0[r] = fexp2(fmaf(S0[kt][r], C1, fmaf(-dp0, dp0, mb)));
                pr1[r] = fexp2(fmaf(S1[kt][r], C1, fmaf(-dp1, dp1, mb)));
            }
            uint2 pk0, pk1;
            pk0.x = pkbf(pr0[0], pr0[1]);
            pk0.y = pkbf(pr0[2], pr0[3]);
            pk1.x = pkbf(pr1[0], pr1[1]);
            pk1.y = pkbf(pr1[2], pr1[3]);
            *(uint2*)&PT[prow0][kt * 16 + quad * 4] = pk0;
            *(uint2*)&PT[prow1][kt * 16 + quad * 4] = pk1;
        }

        // P fragments (wave-private rows; same-wave cross-lane after lgkm)
        const short8 pB00 = *(const short8*)&PT[prow0][quad * 8];
        const short8 pB01 = *(const short8*)&PT[prow0][32 + quad * 8];
        const short8 pB10 = *(const short8*)&PT[prow1][quad * 8];
        const short8 pB11 = *(const short8*)&PT[prow1][32 + quad * 8];
        Lac0 = __builtin_amdgcn_mfma_f32_16x16x32_bf16(ones, pB00, Lac0, 0, 0, 0);
        Lac0 = __builtin_amdgcn_mfma_f32_16x16x32_bf16(ones, pB01, Lac0, 0, 0, 0);
        Lac1 = __builtin_amdgcn_mfma_f32_16x16x32_bf16(ones, pB10, Lac1, 0, 0, 0);
        Lac1 = __builtin_amdgcn_mfma_f32_16x16x32_bf16(ones, pB11, Lac1, 0, 0, 0);

        // PV for BOTH halves; V from regs (safe vs. re-stage of buf pb)
#pragma unroll
        for (int mt = 0; mt < 4; mt++) {
            O0[mt] = __builtin_amdgcn_mfma_f32_16x16x32_bf16(va[mt], pB00, O0[mt], 0, 0, 0);
            O0[mt] = __builtin_amdgcn_mfma_f32_16x16x32_bf16(vb[mt], pB01, O0[mt], 0, 0, 0);
            O1[mt] = __builtin_amdgcn_mfma_f32_16x16x32_bf16(va[mt], pB10, O1[mt], 0, 0, 0);
            O1[mt] = __builtin_amdgcn_mfma_f32_16x16x32_bf16(vb[mt], pB11, O1[mt], 0, 0, 0);
        }
    }
#undef ATT_STAGE

    {
        const float inv0 = 1.0f / Lac0[0];
        u16* dst0 = Xa + ((size_t)qrow0 * BQ + b) * HID + h * DH;
#pragma unroll
        for (int mt = 0; mt < 4; mt++) {
            uint2 pk2;
            pk2.x = pkbf(O0[mt][0] * inv0, O0[mt][1] * inv0);
            pk2.y = pkbf(O0[mt][2] * inv0, O0[mt][3] * inv0);
            *(uint2*)(dst0 + mt * 16 + quad * 4) = pk2;
        }
        const float inv1 = 1.0f / Lac1[0];
        u16* dst1 = Xa + ((size_t)qrow1 * BQ + b) * HID + h * DH;
#pragma unroll
        for (int mt = 0; mt < 4; mt++) {
            uint2 pk2;
            pk2.x = pkbf(O1[mt][0] * inv1, O1[mt][1] * inv1);
            pk2.y = pkbf(O1[mt][2] * inv1, O1[mt][3] * inv1);
            *(uint2*)(dst1 + mt * 16 + quad * 4) = pk2;
        }
    }
}

// ---------------------------------------------------------------------------
extern "C" void kernel_launch(void* const* d_in, const int* in_sizes, int n_in,
                              void* d_out, int out_size, void* d_ws, size_t ws_size,
                              hipStream_t stream) {
    const float* q    = (const float*)d_in[0];
    const float* k    = (const float*)d_in[1];
    const float* v    = (const float*)d_in[2];
    const void*  mask = d_in[3];
    const float* wq   = (const float*)d_in[4];
    const float* wk   = (const float*)d_in[5];
    const float* wv   = (const float*)d_in[6];
    const float* wfc  = (const float*)d_in[7];
    const float* bq   = (const float*)d_in[8];
    const float* bk   = (const float*)d_in[9];
    const float* bv   = (const float*)d_in[10];
    const float* bfc  = (const float*)d_in[11];
    const float* tao  = (const float*)d_in[12];

    const size_t NE = (size_t)LQ * BQ * HID;  // 4,194,304
    const size_t NW = (size_t)HID * HID;      // 1,048,576
    u16* base = (u16*)d_ws;
    u16* Qp    = base;            // [bh][l][d]
    u16* Kp    = base + NE;       // [bh][l][d]
    u16* Vtp   = base + 2 * NE;   // [bh][d][l]
    u16* Xa    = base + 3 * NE;
    u16* qbf   = base + 4 * NE;
    u16* kbf   = base + 5 * NE;
    u16* vbf   = base + 6 * NE;
    u16* wqbf  = base + 7 * NE;
    u16* wkbf  = wqbf + NW;
    u16* wvbf  = wkbf + NW;
    u16* wfcbf = wvbf + NW;
    float* maskF = (float*)(wfcbf + NW);

    CastArgs ca;
    ca.s[0] = q;   ca.d[0] = qbf;   ca.n[0] = (int)NE;
    ca.s[1] = k;   ca.d[1] = kbf;   ca.n[1] = (int)NE;
    ca.s[2] = v;   ca.d[2] = vbf;   ca.n[2] = (int)NE;
    ca.s[3] = wq;  ca.d[3] = wqbf;  ca.n[3] = (int)NW;
    ca.s[4] = wk;  ca.d[4] = wkbf;  ca.n[4] = (int)NW;
    ca.s[5] = wv;  ca.d[5] = wvbf;  ca.n[5] = (int)NW;
    ca.s[6] = wfc; ca.d[6] = wfcbf; ca.n[6] = (int)NW;
    ca.mraw = (const unsigned char*)mask;
    ca.mout = maskF;
    ca.mn = BQ * LQ;
    castw<<<dim3(256, 8), 256, 0, stream>>>(ca);

    QkvArgs ga;
    ga.A[0] = qbf;  ga.W[0] = wqbf;  ga.bias[0] = bq;  ga.out[0] = Qp;
    ga.A[1] = kbf;  ga.W[1] = wkbf;  ga.bias[1] = bk;  ga.out[1] = Kp;
    ga.A[2] = vbf;  ga.W[2] = wvbf;  ga.bias[2] = bv;  ga.out[2] = Vtp;
    gemm_qkv<<<dim3(32, 8, 3), 512, 0, stream>>>(ga);

    attn_kernel<<<dim3(32, 16), 256, 0, stream>>>(Qp, Kp, Vtp, maskF, tao, Xa);

    gemm_fc<<<dim3(32, 16), 256, 0, stream>>>(Xa, wfcbf, bfc, (float*)d_out);
}